// Round 3
// baseline (3515.288 us; speedup 1.0000x reference)
//
#include <hip/hip_runtime.h>

#define Hh 8
#define Bb 4
#define Ll 4096
#define Cc 1024
#define DH 128
#define DI 256
#define KK 4
#define RR 8
#define NN 16

typedef unsigned short u16;

__device__ __forceinline__ float bf2f(u16 u) {
  union { unsigned int i; float f; } v; v.i = ((unsigned int)u) << 16; return v.f;
}

template<typename T> __device__ __forceinline__ float ld1(const T* p);
template<> __device__ __forceinline__ float ld1<float>(const float* p) { return *p; }
template<> __device__ __forceinline__ float ld1<u16>(const u16* p) { return bf2f(*p); }

template<typename T> __device__ __forceinline__ void ld8(const T* p, float* w);
template<> __device__ __forceinline__ void ld8<float>(const float* p, float* w) {
  float4 a = *(const float4*)p, b = *(const float4*)(p + 4);
  w[0]=a.x; w[1]=a.y; w[2]=a.z; w[3]=a.w; w[4]=b.x; w[5]=b.y; w[6]=b.z; w[7]=b.w;
}
template<> __device__ __forceinline__ void ld8<u16>(const u16* p, float* w) {
  ushort4 a = *(const ushort4*)p, b = *(const ushort4*)(p + 4);
  w[0]=bf2f(a.x); w[1]=bf2f(a.y); w[2]=bf2f(a.z); w[3]=bf2f(a.w);
  w[4]=bf2f(b.x); w[5]=bf2f(b.y); w[6]=bf2f(b.z); w[7]=bf2f(b.w);
}

template<typename T> __device__ __forceinline__ void ld4v(const T* p, float* w);
template<> __device__ __forceinline__ void ld4v<float>(const float* p, float* w) {
  float4 a = *(const float4*)p; w[0]=a.x; w[1]=a.y; w[2]=a.z; w[3]=a.w;
}
template<> __device__ __forceinline__ void ld4v<u16>(const u16* p, float* w) {
  ushort4 a = *(const ushort4*)p; w[0]=bf2f(a.x); w[1]=bf2f(a.y); w[2]=bf2f(a.z); w[3]=bf2f(a.w);
}

template<typename T> __device__ __forceinline__ void st1(T* p, float v);
template<> __device__ __forceinline__ void st1<float>(float* p, float v) { *p = v; }
template<> __device__ __forceinline__ void st1<u16>(u16* p, float v) {
  union { float f; unsigned int i; } u; u.f = v;
  unsigned int lsb = (u.i >> 16) & 1; u.i += 0x7FFFu + lsb; *p = (u16)(u.i >> 16);
}

__device__ __forceinline__ float dot8(float4 a, float4 b, const float* w) {
  return a.x*w[0]+a.y*w[1]+a.z*w[2]+a.w*w[3]+b.x*w[4]+b.y*w[5]+b.z*w[6]+b.w*w[7];
}
// sanitize cross-kernel reads: NaN->0, clamp. Diagnostic aid, cannot fake a pass.
__device__ __forceinline__ float fin(float v) {
  v = (v == v) ? v : 0.f;
  return fminf(fmaxf(v, -1e4f), 1e4f);
}

// dtype detector: sample even ushort indices of x. bf16 data -> sane exponents
// (~99.8%); f32 data -> those are mantissa bits (~6% sane). flag=1 means bf16.
__global__ void detect_dtype(const u16* xu, int* flag) {
  __shared__ int cnt;
  if (threadIdx.x == 0) cnt = 0;
  __syncthreads();
  u16 u = xu[(size_t)threadIdx.x * 65536u];
  int e = (u >> 7) & 0xFF;
  atomicAdd(&cnt, (e >= 118 && e <= 132) ? 1 : 0);
  __syncthreads();
  if (threadIdx.x == 0) *flag = (cnt > 128) ? 1 : 0;
}

// ---------------- K1: in_proj + causal conv(K=4) + SiLU -----------------
template<typename T>
__device__ void k1_body(const T* x, const T* w_in, const T* conv_w, const T* conv_b,
                        float* uc, float* zb, int h0, int b0, int bg_sh, int tsh,
                        int l_base, char* smem)
{
  const int TILE = 16, HALO = 3, TT = 19;
  float (*x_s)[DH] = (float(*)[DH])smem;
  int wg = blockIdx.x;
  int tmask = (1 << tsh) - 1;
  int lt = wg & tmask, c = wg >> tsh;
  int bl = c & ((1 << bg_sh) - 1), hl = c >> bg_sh;
  int h = h0 + hl, b = b0 + bl;
  int l0 = l_base + lt * TILE;
  int tid = threadIdx.x;

  for (int idx = tid; idx < TT*DH; idx += 256) {
    int t = idx >> 7, d = idx & 127;
    int l = l0 - HALO + t;
    x_s[t][d] = (l >= 0) ? ld1(x + ((size_t)(b*Ll + l))*Cc + h*DH + d) : 0.f;
  }
  __syncthreads();

  int e = tid;
  const T* wu = w_in + ((size_t)h*(2*DI) + e)*DH;
  const T* wz = wu + (size_t)DI*DH;
  float accu[TT], accz[TILE];
  #pragma unroll
  for (int t = 0; t < TT; t++) accu[t] = 0.f;
  #pragma unroll
  for (int t = 0; t < TILE; t++) accz[t] = 0.f;

  for (int ds = 0; ds < DH; ds += 8) {
    float wuv[8], wzv[8];
    ld8(wu + ds, wuv); ld8(wz + ds, wzv);
    #pragma unroll
    for (int t = 0; t < TT; t++) {
      float4 xa = *(const float4*)&x_s[t][ds];
      float4 xb = *(const float4*)&x_s[t][ds+4];
      accu[t] += dot8(xa, xb, wuv);
      if (t >= HALO) accz[t-HALO] += dot8(xa, xb, wzv);
    }
  }

  float cw[4]; ld4v(conv_w + ((size_t)h*DI + e)*KK, cw);
  float cb = ld1(conv_b + h*DI + e);
  size_t base = ((size_t)(c << (tsh+4)) + lt*TILE) * DI;
  #pragma unroll
  for (int t = 0; t < TILE; t++) {
    float acc = cb + accu[t]*cw[0] + accu[t+1]*cw[1] + accu[t+2]*cw[2] + accu[t+3]*cw[3];
    float s = 1.f / (1.f + __expf(-acc));
    uc[base + (size_t)t*DI + e] = acc * s;
    zb[base + (size_t)t*DI + e] = accz[t];
  }
}

__global__ __launch_bounds__(256) void k1(const void* x, const void* w_in,
    const void* conv_w, const void* conv_b, float* uc, float* zb,
    const int* flag, int h0, int b0, int bg_sh, int tsh, int l_base)
{
  extern __shared__ char smem[];
  if (*flag) k1_body<u16>((const u16*)x, (const u16*)w_in, (const u16*)conv_w,
                          (const u16*)conv_b, uc, zb, h0, b0, bg_sh, tsh, l_base, smem);
  else       k1_body<float>((const float*)x, (const float*)w_in, (const float*)conv_w,
                          (const float*)conv_b, uc, zb, h0, b0, bg_sh, tsh, l_base, smem);
}

// ---------------- K2: x_proj -> raw dt(8) + B(16) + C(16) per token -----
template<typename T>
__device__ void k2_body(const float* uc, const T* xp_w, float* dtbc,
                        int h0, int bg_sh, int tsh, char* smem)
{
  const int TILE = 16;
  float (*uc_s)[DI] = (float(*)[DI])smem;
  int wg = blockIdx.x;
  int tmask = (1 << tsh) - 1;
  int lt = wg & tmask, c = wg >> tsh;
  int h = h0 + (c >> bg_sh);
  int tid = threadIdx.x;
  size_t tokbase = (size_t)(c << (tsh+4)) + lt*TILE;

  for (int idx = tid; idx < TILE*DI; idx += 256)
    uc_s[idx >> 8][idx & 255] = fin(uc[tokbase*DI + idx]);
  __syncthreads();

  for (int oi = tid; oi < TILE*40; oi += 256) {
    int tok = oi / 40, ee = oi - tok*40;
    const T* wrow = xp_w + ((size_t)h*40 + ee)*DI;
    float acc = 0.f;
    for (int ds = 0; ds < DI; ds += 8) {
      float w[8]; ld8(wrow + ds, w);
      float4 xa = *(const float4*)&uc_s[tok][ds];
      float4 xb = *(const float4*)&uc_s[tok][ds+4];
      acc += dot8(xa, xb, w);
    }
    dtbc[(tokbase + tok)*40 + ee] = acc;
  }
}

__global__ __launch_bounds__(256) void k2(const float* uc, const void* xp_w,
    float* dtbc, const int* flag, int h0, int bg_sh, int tsh)
{
  extern __shared__ char smem[];
  if (*flag) k2_body<u16>(uc, (const u16*)xp_w, dtbc, h0, bg_sh, tsh, smem);
  else       k2_body<float>(uc, (const float*)xp_w, dtbc, h0, bg_sh, tsh, smem);
}

// ---------------- K3: dt_proj+softplus fused into selective scan --------
struct K3S {
  float2 du[64][16];
  float2 bc[64][16];
  float  dts[64][8];
  float  ys[16][68];
  float  wdt[16][8];
  float  bias[16];
  float  Dg[16];
};

template<typename T>
__device__ void k3_body(float* uc, const float* zb, const float* dtbc,
                        const T* dtp_w, const T* dtp_b, const T* A_log, const T* Dp,
                        float* state_buf, int h0, int bg_sh, int tsh, int l_base,
                        char* smem)
{
  K3S* S = (K3S*)smem;
  const int TL = 64;
  int wg = blockIdx.x;
  int g = wg & 15, c = wg >> 4;
  int h = h0 + (c >> bg_sh);
  int tid = threadIdx.x;
  int dloc = tid >> 4, n = tid & 15;
  int ch0 = g * 16;
  int seg = 16 << tsh;
  size_t slice = (size_t)c << (tsh+4);

  if (tid < 128) S->wdt[tid >> 3][tid & 7] =
      ld1(dtp_w + ((size_t)(h*DI + ch0 + (tid >> 3)))*RR + (tid & 7));
  if (tid < 16) {
    S->bias[tid] = ld1(dtp_b + h*DI + ch0 + tid);
    S->Dg[tid]   = ld1(Dp    + h*DI + ch0 + tid);
  }
  float a = -__expf(ld1(A_log + ((size_t)(h*DI + ch0 + dloc))*NN + n));
  size_t sidx = ((size_t)c*DI + ch0 + dloc)*NN + n;
  float state = (l_base == 0) ? 0.f : state_buf[sidx];
  __syncthreads();

  for (int t0 = 0; t0 < seg; t0 += TL) {
    for (int idx = tid; idx < TL*8; idx += 256) {
      int t = idx >> 3, r = idx & 7;
      S->dts[t][r] = fin(dtbc[(slice + t0 + t)*40 + r]);
    }
    for (int idx = tid; idx < TL*32; idx += 256) {
      int t = idx >> 5, j = idx & 31;
      float v = fin(dtbc[(slice + t0 + t)*40 + 8 + j]);  // B then C, both at +8+j
      ((float*)&S->bc[t][0])[(j < 16) ? (2*j) : (2*(j-16)+1)] = v;
    }
    __syncthreads();
    for (int idx = tid; idx < TL*16; idx += 256) {
      int t = idx >> 4, cc = idx & 15;
      const float* dr = S->dts[t];
      const float* wr = S->wdt[cc];
      float v = S->bias[cc];
      #pragma unroll
      for (int r = 0; r < 8; r++) v += dr[r]*wr[r];
      float delta = (v > 15.f) ? v : log1pf(__expf(v));
      float uv = fin(uc[(slice + t0 + t)*DI + ch0 + cc]);
      S->du[t][cc] = make_float2(delta, delta * uv);
    }
    __syncthreads();
    #pragma unroll
    for (int t4 = 0; t4 < TL; t4 += 4) {
      float yv[4];
      #pragma unroll
      for (int j = 0; j < 4; j++) {
        float2 dx  = S->du[t4+j][dloc];
        float2 bcv = S->bc[t4+j][n];
        float dA = __expf(dx.x * a);
        state = fmaf(dA, state, dx.y * bcv.x);
        float p = state * bcv.y;
        p += __shfl_xor(p, 1, 64);
        p += __shfl_xor(p, 2, 64);
        p += __shfl_xor(p, 4, 64);
        p += __shfl_xor(p, 8, 64);
        yv[j] = p;
      }
      if (n == 0) *(float4*)&S->ys[dloc][t4] = make_float4(yv[0], yv[1], yv[2], yv[3]);
    }
    __syncthreads();
    for (int idx = tid; idx < TL*16; idx += 256) {
      int t = idx >> 4, cc = idx & 15;
      size_t gi = (slice + t0 + t)*DI + ch0 + cc;
      float y  = S->ys[cc][t];
      float uv = fin(uc[gi]);
      float zv = fin(zb[gi]);
      float sz = zv / (1.f + __expf(-zv));
      uc[gi] = (y + uv*S->Dg[cc]) * sz;   // y written in-place over uc
    }
    __syncthreads();
  }
  state_buf[sidx] = state;
}

__global__ __launch_bounds__(256) void k3(float* uc, const float* zb, const float* dtbc,
    const void* dtp_w, const void* dtp_b, const void* A_log, const void* Dp,
    float* state_buf, const int* flag, int h0, int bg_sh, int tsh, int l_base)
{
  extern __shared__ char smem[];
  if (*flag) k3_body<u16>(uc, zb, dtbc, (const u16*)dtp_w, (const u16*)dtp_b,
                          (const u16*)A_log, (const u16*)Dp, state_buf,
                          h0, bg_sh, tsh, l_base, smem);
  else       k3_body<float>(uc, zb, dtbc, (const float*)dtp_w, (const float*)dtp_b,
                          (const float*)A_log, (const float*)Dp, state_buf,
                          h0, bg_sh, tsh, l_base, smem);
}

// ---------------- K4: out_proj ------------------------------------------
template<typename T>
__device__ void k4_body(const float* yb, const T* w_out, T* out,
                        int h0, int b0, int bg_sh, int tsh, int l_base, char* smem)
{
  const int TILE = 16;
  float (*y_s)[DI] = (float(*)[DI])smem;
  int wg = blockIdx.x;
  int tmask = (1 << tsh) - 1;
  int lt = wg & tmask, c = wg >> tsh;
  int bl = c & ((1 << bg_sh) - 1), hl = c >> bg_sh;
  int h = h0 + hl, b = b0 + bl;
  int tid = threadIdx.x;
  size_t tokbase = (size_t)(c << (tsh+4)) + lt*TILE;
  int l0 = l_base + lt*TILE;
  for (int idx = tid; idx < TILE*DI; idx += 256)
    y_s[idx >> 8][idx & 255] = fin(yb[tokbase*DI + idx]);
  __syncthreads();
  int o = tid & 63, tg = tid >> 6;
  const T* w0r = w_out + ((size_t)h*DH + o)*DI;
  const T* w1r = w0r + (size_t)64*DI;
  float acc0[4] = {0,0,0,0}, acc1[4] = {0,0,0,0};
  for (int ds = 0; ds < DI; ds += 8) {
    float w0[8], w1[8];
    ld8(w0r + ds, w0); ld8(w1r + ds, w1);
    #pragma unroll
    for (int tt = 0; tt < 4; tt++) {
      float4 xa = *(const float4*)&y_s[tg*4+tt][ds];
      float4 xb = *(const float4*)&y_s[tg*4+tt][ds+4];
      acc0[tt] += dot8(xa, xb, w0);
      acc1[tt] += dot8(xa, xb, w1);
    }
  }
  #pragma unroll
  for (int tt = 0; tt < 4; tt++) {
    int l = l0 + tg*4 + tt;
    size_t ob = ((size_t)(b*Ll + l))*Cc + (size_t)h*DH;
    st1(out + ob + o,      acc0[tt]);
    st1(out + ob + o + 64, acc1[tt]);
  }
}

__global__ __launch_bounds__(256) void k4(const float* yb, const void* w_out,
    void* out, const int* flag, int h0, int b0, int bg_sh, int tsh, int l_base)
{
  extern __shared__ char smem[];
  if (*flag) k4_body<u16>(yb, (const u16*)w_out, (u16*)out, h0, b0, bg_sh, tsh, l_base, smem);
  else       k4_body<float>(yb, (const float*)w_out, (float*)out, h0, b0, bg_sh, tsh, l_base, smem);
}

extern "C" void kernel_launch(void* const* d_in, const int* in_sizes, int n_in,
                              void* d_out, int out_size, void* d_ws, size_t ws_size,
                              hipStream_t stream)
{
  const void* x      = d_in[0];
  const void* w_in   = d_in[1];
  const void* conv_w = d_in[2];
  const void* conv_b = d_in[3];
  const void* xp_w   = d_in[4];
  const void* dtp_w  = d_in[5];
  const void* dtp_b  = d_in[6];
  const void* A_log  = d_in[7];
  const void* Dp     = d_in[8];
  const void* w_out  = d_in[9];
  (void)in_sizes; (void)n_in; (void)out_size;

  int* flag = (int*)d_ws;
  detect_dtype<<<1, 256, 0, stream>>>((const u16*)x, flag);

  // chunk ladder: (HG heads, BG batches, tsh: seg = 16<<tsh tokens)
  static const int HGs[] = {8,4,2,1,1,1,1,1,1};
  static const int BGs[] = {4,4,4,4,2,1,1,1,1};
  static const int TSs[] = {8,8,8,8,8,8,6,4,2};
  size_t avail = (ws_size > 256) ? ws_size - 256 : 0;
  int sel = 8;
  for (int i = 0; i < 9; i++) {
    size_t S = (size_t)16 << TSs[i];
    size_t per = S*DI*4*2 + S*40*4 + (size_t)DI*NN*4;
    if ((size_t)HGs[i]*BGs[i]*per <= avail) { sel = i; break; }
  }
  int HG = HGs[sel], BG = BGs[sel], tsh = TSs[sel];
  int bg_sh = (BG == 4) ? 2 : (BG == 2) ? 1 : 0;
  int NCH = HG * BG;
  int tps = 1 << tsh;
  int SEG = 16 << tsh;

  float* uc    = (float*)((char*)d_ws + 256);
  float* zb    = uc    + (size_t)NCH*SEG*DI;
  float* dtbc  = zb    + (size_t)NCH*SEG*DI;
  float* state = dtbc  + (size_t)NCH*SEG*40;

  size_t sm1 = 19*DH*4;
  size_t sm2 = 16*DI*4;
  size_t sm3 = sizeof(K3S);
  size_t sm4 = 16*DI*4;
  dim3 blk(256);

  for (int h0 = 0; h0 < Hh; h0 += HG)
    for (int b0 = 0; b0 < Bb; b0 += BG)
      for (int l_base = 0; l_base < Ll; l_base += SEG) {
        k1<<<dim3(NCH*tps), blk, sm1, stream>>>(x, w_in, conv_w, conv_b, uc, zb,
                                                flag, h0, b0, bg_sh, tsh, l_base);
        k2<<<dim3(NCH*tps), blk, sm2, stream>>>(uc, xp_w, dtbc, flag, h0, bg_sh, tsh);
        k3<<<dim3(NCH*16),  blk, sm3, stream>>>(uc, zb, dtbc, dtp_w, dtp_b, A_log, Dp,
                                                state, flag, h0, bg_sh, tsh, l_base);
        k4<<<dim3(NCH*tps), blk, sm4, stream>>>(uc, w_out, d_out, flag,
                                                h0, b0, bg_sh, tsh, l_base);
      }
}

// Round 4
// 2821.992 us; speedup vs baseline: 1.2457x; 1.2457x over previous
//
#include <hip/hip_runtime.h>

#define Hh 8
#define Bb 4
#define Ll 4096
#define Cc 1024
#define DH 128
#define DI 256
#define KK 4
#define RR 8
#define NN 16

typedef unsigned short u16;

__device__ __forceinline__ float bf2f(u16 u) {
  union { unsigned int i; float f; } v; v.i = ((unsigned int)u) << 16; return v.f;
}

template<typename T> __device__ __forceinline__ float ld1(const T* p);
template<> __device__ __forceinline__ float ld1<float>(const float* p) { return *p; }
template<> __device__ __forceinline__ float ld1<u16>(const u16* p) { return bf2f(*p); }

template<typename T> __device__ __forceinline__ void ld8(const T* p, float* w);
template<> __device__ __forceinline__ void ld8<float>(const float* p, float* w) {
  float4 a = *(const float4*)p, b = *(const float4*)(p + 4);
  w[0]=a.x; w[1]=a.y; w[2]=a.z; w[3]=a.w; w[4]=b.x; w[5]=b.y; w[6]=b.z; w[7]=b.w;
}
template<> __device__ __forceinline__ void ld8<u16>(const u16* p, float* w) {
  ushort4 a = *(const ushort4*)p, b = *(const ushort4*)(p + 4);
  w[0]=bf2f(a.x); w[1]=bf2f(a.y); w[2]=bf2f(a.z); w[3]=bf2f(a.w);
  w[4]=bf2f(b.x); w[5]=bf2f(b.y); w[6]=bf2f(b.z); w[7]=bf2f(b.w);
}

template<typename T> __device__ __forceinline__ void ld4v(const T* p, float* w);
template<> __device__ __forceinline__ void ld4v<float>(const float* p, float* w) {
  float4 a = *(const float4*)p; w[0]=a.x; w[1]=a.y; w[2]=a.z; w[3]=a.w;
}
template<> __device__ __forceinline__ void ld4v<u16>(const u16* p, float* w) {
  ushort4 a = *(const ushort4*)p; w[0]=bf2f(a.x); w[1]=bf2f(a.y); w[2]=bf2f(a.z); w[3]=bf2f(a.w);
}

template<typename T> __device__ __forceinline__ void st1(T* p, float v);
template<> __device__ __forceinline__ void st1<float>(float* p, float v) { *p = v; }
template<> __device__ __forceinline__ void st1<u16>(u16* p, float v) {
  union { float f; unsigned int i; } u; u.f = v;
  unsigned int lsb = (u.i >> 16) & 1; u.i += 0x7FFFu + lsb; *p = (u16)(u.i >> 16);
}

__device__ __forceinline__ float dot8(float4 a, float4 b, const float* w) {
  return a.x*w[0]+a.y*w[1]+a.z*w[2]+a.w*w[3]+b.x*w[4]+b.y*w[5]+b.z*w[6]+b.w*w[7];
}
__device__ __forceinline__ float fin(float v) {
  v = (v == v) ? v : 0.f;
  return fminf(fmaxf(v, -1e4f), 1e4f);
}

// dtype detector (flag=1 -> bf16 inputs). f32 inputs confirmed in R3 (flag=0)
// but kept: costs ~2 us, removes a failure mode.
__global__ void detect_dtype(const u16* xu, int* flag) {
  __shared__ int cnt;
  if (threadIdx.x == 0) cnt = 0;
  __syncthreads();
  u16 u = xu[(size_t)threadIdx.x * 65536u];
  int e = (u >> 7) & 0xFF;
  atomicAdd(&cnt, (e >= 118 && e <= 132) ? 1 : 0);
  __syncthreads();
  if (threadIdx.x == 0) *flag = (cnt > 128) ? 1 : 0;
}

// ---------------- K1: in_proj + causal conv(K=4) + SiLU -----------------
template<typename T>
__device__ void k1_body(const T* x, const T* w_in, const T* conv_w, const T* conv_b,
                        float* uc, float* zb, int h0, int b0, int bg_sh, int tsh,
                        int l_base, char* smem)
{
  const int TILE = 16, HALO = 3, TT = 19;
  float (*x_s)[DH] = (float(*)[DH])smem;
  int wg = blockIdx.x;
  int tmask = (1 << tsh) - 1;
  int lt = wg & tmask, c = wg >> tsh;
  int bl = c & ((1 << bg_sh) - 1), hl = c >> bg_sh;
  int h = h0 + hl, b = b0 + bl;
  int l0 = l_base + lt * TILE;
  int tid = threadIdx.x;

  for (int idx = tid; idx < TT*DH; idx += 256) {
    int t = idx >> 7, d = idx & 127;
    int l = l0 - HALO + t;
    x_s[t][d] = (l >= 0) ? ld1(x + ((size_t)(b*Ll + l))*Cc + h*DH + d) : 0.f;
  }
  __syncthreads();

  int e = tid;
  const T* wu = w_in + ((size_t)h*(2*DI) + e)*DH;
  const T* wz = wu + (size_t)DI*DH;
  float accu[TT], accz[TILE];
  #pragma unroll
  for (int t = 0; t < TT; t++) accu[t] = 0.f;
  #pragma unroll
  for (int t = 0; t < TILE; t++) accz[t] = 0.f;

  for (int ds = 0; ds < DH; ds += 8) {
    float wuv[8], wzv[8];
    ld8(wu + ds, wuv); ld8(wz + ds, wzv);
    #pragma unroll
    for (int t = 0; t < TT; t++) {
      float4 xa = *(const float4*)&x_s[t][ds];
      float4 xb = *(const float4*)&x_s[t][ds+4];
      accu[t] += dot8(xa, xb, wuv);
      if (t >= HALO) accz[t-HALO] += dot8(xa, xb, wzv);
    }
  }

  float cw[4]; ld4v(conv_w + ((size_t)h*DI + e)*KK, cw);
  float cb = ld1(conv_b + h*DI + e);
  size_t base = ((size_t)(c << (tsh+4)) + lt*TILE) * DI;
  #pragma unroll
  for (int t = 0; t < TILE; t++) {
    float acc = cb + accu[t]*cw[0] + accu[t+1]*cw[1] + accu[t+2]*cw[2] + accu[t+3]*cw[3];
    float s = 1.f / (1.f + __expf(-acc));
    uc[base + (size_t)t*DI + e] = acc * s;
    zb[base + (size_t)t*DI + e] = accz[t];
  }
}

__global__ __launch_bounds__(256) void k1(const void* x, const void* w_in,
    const void* conv_w, const void* conv_b, float* uc, float* zb,
    const int* flag, int h0, int b0, int bg_sh, int tsh, int l_base)
{
  extern __shared__ char smem[];
  if (*flag) k1_body<u16>((const u16*)x, (const u16*)w_in, (const u16*)conv_w,
                          (const u16*)conv_b, uc, zb, h0, b0, bg_sh, tsh, l_base, smem);
  else       k1_body<float>((const float*)x, (const float*)w_in, (const float*)conv_w,
                          (const float*)conv_b, uc, zb, h0, b0, bg_sh, tsh, l_base, smem);
}

// ---------------- K2: x_proj -> raw dt(8) + B(16) + C(16) per token -----
template<typename T>
__device__ void k2_body(const float* uc, const T* xp_w, float* dtbc,
                        int h0, int bg_sh, int tsh, char* smem)
{
  const int TILE = 16;
  float (*uc_s)[DI] = (float(*)[DI])smem;
  int wg = blockIdx.x;
  int tmask = (1 << tsh) - 1;
  int lt = wg & tmask, c = wg >> tsh;
  int h = h0 + (c >> bg_sh);
  int tid = threadIdx.x;
  size_t tokbase = (size_t)(c << (tsh+4)) + lt*TILE;

  for (int idx = tid; idx < TILE*DI; idx += 256)
    uc_s[idx >> 8][idx & 255] = fin(uc[tokbase*DI + idx]);
  __syncthreads();

  for (int oi = tid; oi < TILE*40; oi += 256) {
    int tok = oi / 40, ee = oi - tok*40;
    const T* wrow = xp_w + ((size_t)h*40 + ee)*DI;
    float acc = 0.f;
    for (int ds = 0; ds < DI; ds += 8) {
      float w[8]; ld8(wrow + ds, w);
      float4 xa = *(const float4*)&uc_s[tok][ds];
      float4 xb = *(const float4*)&uc_s[tok][ds+4];
      acc += dot8(xa, xb, w);
    }
    dtbc[(tokbase + tok)*40 + ee] = acc;
  }
}

__global__ __launch_bounds__(256) void k2(const float* uc, const void* xp_w,
    float* dtbc, const int* flag, int h0, int bg_sh, int tsh)
{
  extern __shared__ char smem[];
  if (*flag) k2_body<u16>(uc, (const u16*)xp_w, dtbc, h0, bg_sh, tsh, smem);
  else       k2_body<float>(uc, (const float*)xp_w, dtbc, h0, bg_sh, tsh, smem);
}

// ------- K3a: per-L-chunk local scan -> h_local_end[d,n] + sum_delta[d] --
struct K3AS {
  float2 du[64][16];   // {delta, delta*u}
  float  Bv[64][16];
  float  dts[64][8];
  float  wdt[16][8];
  float  bias[16];
};

template<typename T>
__device__ void k3a_body(const float* uc, const float* dtbc,
                         const T* dtp_w, const T* dtp_b, const T* A_log,
                         float* hloc, float* Sb,
                         int h0, int bg_sh, int lcsh, int nlsh, char* smem)
{
  K3AS* S = (K3AS*)smem;
  const int TL = 64;
  int wg = blockIdx.x;
  int g = wg & 15;
  int nl = (wg >> 4) & ((1 << nlsh) - 1);
  int c = wg >> (4 + nlsh);
  int h = h0 + (c >> bg_sh);
  int tid = threadIdx.x;
  int dloc = tid >> 4, n = tid & 15;
  int ch0 = g * 16;
  int NL = 1 << nlsh, LC = 1 << lcsh;
  size_t tok0 = ((size_t)(c*NL + nl)) << lcsh;

  if (tid < 128) S->wdt[tid >> 3][tid & 7] =
      ld1(dtp_w + ((size_t)(h*DI + ch0 + (tid >> 3)))*RR + (tid & 7));
  if (tid < 16) S->bias[tid] = ld1(dtp_b + h*DI + ch0 + tid);
  float a = -__expf(ld1(A_log + ((size_t)(h*DI + ch0 + dloc))*NN + n));
  float state = 0.f, ssum = 0.f;
  __syncthreads();

  for (int t0 = 0; t0 < LC; t0 += TL) {
    for (int idx = tid; idx < TL*8; idx += 256) {
      int t = idx >> 3, r = idx & 7;
      S->dts[t][r] = fin(dtbc[(tok0 + t0 + t)*40 + r]);
    }
    for (int idx = tid; idx < TL*16; idx += 256) {
      int t = idx >> 4, j = idx & 15;
      S->Bv[t][j] = fin(dtbc[(tok0 + t0 + t)*40 + 8 + j]);
    }
    __syncthreads();
    for (int idx = tid; idx < TL*16; idx += 256) {
      int t = idx >> 4, cc = idx & 15;
      const float* dr = S->dts[t];
      const float* wr = S->wdt[cc];
      float v = S->bias[cc];
      #pragma unroll
      for (int r = 0; r < 8; r++) v += dr[r]*wr[r];
      float delta = (v > 15.f) ? v : log1pf(__expf(v));
      float uv = fin(uc[(tok0 + t0 + t)*DI + ch0 + cc]);
      S->du[t][cc] = make_float2(delta, delta * uv);
    }
    __syncthreads();
    #pragma unroll 4
    for (int t = 0; t < TL; t++) {
      float2 dx = S->du[t][dloc];
      float bv = S->Bv[t][n];
      state = fmaf(__expf(dx.x * a), state, dx.y * bv);
      ssum += dx.x;
    }
    __syncthreads();
  }
  hloc[((size_t)(c*NL + nl)*DI + ch0 + dloc)*NN + n] = state;
  if (n == 0) Sb[(size_t)(c*NL + nl)*DI + ch0 + dloc] = ssum;
}

__global__ __launch_bounds__(256) void k3a(const float* uc, const float* dtbc,
    const void* dtp_w, const void* dtp_b, const void* A_log,
    float* hloc, float* Sb, const int* flag, int h0, int bg_sh, int lcsh, int nlsh)
{
  extern __shared__ char smem[];
  if (*flag) k3a_body<u16>(uc, dtbc, (const u16*)dtp_w, (const u16*)dtp_b,
                           (const u16*)A_log, hloc, Sb, h0, bg_sh, lcsh, nlsh, smem);
  else       k3a_body<float>(uc, dtbc, (const float*)dtp_w, (const float*)dtp_b,
                           (const float*)A_log, hloc, Sb, h0, bg_sh, lcsh, nlsh, smem);
}

// ------- K3b: sequential chunk composition; hloc becomes h_in per chunk --
template<typename T>
__device__ void k3b_body(float* hloc, const float* Sb, float* state_buf,
                         const T* A_log, int h0, int bg_sh, int nlsh, int l_base)
{
  int gid = blockIdx.x * 256 + threadIdx.x;
  int c = gid >> 12;            // DI*NN = 4096 per (h,b)
  int r = gid & 4095;
  int d = r >> 4, n = r & 15;
  int h = h0 + (c >> bg_sh);
  int NL = 1 << nlsh;
  float a = -__expf(ld1(A_log + ((size_t)(h*DI + d))*NN + n));
  size_t sidx = ((size_t)c*DI + d)*NN + n;
  float hin = (l_base == 0) ? 0.f : state_buf[sidx];
  for (int k = 0; k < NL; k++) {
    size_t hi = ((size_t)(c*NL + k)*DI + d)*NN + n;
    float tmp = hloc[hi];
    hloc[hi] = hin;
    hin = fmaf(__expf(a * Sb[(size_t)(c*NL + k)*DI + d]), hin, tmp);
  }
  state_buf[sidx] = hin;
}

__global__ __launch_bounds__(256) void k3b(float* hloc, const float* Sb,
    float* state_buf, const void* A_log, const int* flag,
    int h0, int bg_sh, int nlsh, int l_base)
{
  if (*flag) k3b_body<u16>(hloc, Sb, state_buf, (const u16*)A_log, h0, bg_sh, nlsh, l_base);
  else       k3b_body<float>(hloc, Sb, state_buf, (const float*)A_log, h0, bg_sh, nlsh, l_base);
}

// ------- K3c: full scan per chunk from h_in, emit gated output over uc ---
struct K3S {
  float2 du[64][16];
  float2 bc[64][16];
  float  dts[64][8];
  float  ys[16][68];
  float  wdt[16][8];
  float  bias[16];
  float  Dg[16];
};

template<typename T>
__device__ void k3c_body(float* uc, const float* zb, const float* dtbc,
                         const T* dtp_w, const T* dtp_b, const T* A_log, const T* Dp,
                         const float* hloc, int h0, int bg_sh, int lcsh, int nlsh,
                         char* smem)
{
  K3S* S = (K3S*)smem;
  const int TL = 64;
  int wg = blockIdx.x;
  int g = wg & 15;
  int nl = (wg >> 4) & ((1 << nlsh) - 1);
  int c = wg >> (4 + nlsh);
  int h = h0 + (c >> bg_sh);
  int tid = threadIdx.x;
  int dloc = tid >> 4, n = tid & 15;
  int ch0 = g * 16;
  int NL = 1 << nlsh, LC = 1 << lcsh;
  size_t tok0 = ((size_t)(c*NL + nl)) << lcsh;

  if (tid < 128) S->wdt[tid >> 3][tid & 7] =
      ld1(dtp_w + ((size_t)(h*DI + ch0 + (tid >> 3)))*RR + (tid & 7));
  if (tid < 16) {
    S->bias[tid] = ld1(dtp_b + h*DI + ch0 + tid);
    S->Dg[tid]   = ld1(Dp    + h*DI + ch0 + tid);
  }
  float a = -__expf(ld1(A_log + ((size_t)(h*DI + ch0 + dloc))*NN + n));
  float state = hloc[((size_t)(c*NL + nl)*DI + ch0 + dloc)*NN + n];
  __syncthreads();

  for (int t0 = 0; t0 < LC; t0 += TL) {
    for (int idx = tid; idx < TL*8; idx += 256) {
      int t = idx >> 3, r = idx & 7;
      S->dts[t][r] = fin(dtbc[(tok0 + t0 + t)*40 + r]);
    }
    for (int idx = tid; idx < TL*32; idx += 256) {
      int t = idx >> 5, j = idx & 31;
      float v = fin(dtbc[(tok0 + t0 + t)*40 + 8 + j]);
      ((float*)&S->bc[t][0])[(j < 16) ? (2*j) : (2*(j-16)+1)] = v;
    }
    __syncthreads();
    for (int idx = tid; idx < TL*16; idx += 256) {
      int t = idx >> 4, cc = idx & 15;
      const float* dr = S->dts[t];
      const float* wr = S->wdt[cc];
      float v = S->bias[cc];
      #pragma unroll
      for (int r = 0; r < 8; r++) v += dr[r]*wr[r];
      float delta = (v > 15.f) ? v : log1pf(__expf(v));
      float uv = fin(uc[(tok0 + t0 + t)*DI + ch0 + cc]);
      S->du[t][cc] = make_float2(delta, delta * uv);
    }
    __syncthreads();
    #pragma unroll
    for (int t4 = 0; t4 < TL; t4 += 4) {
      float yv[4];
      #pragma unroll
      for (int j = 0; j < 4; j++) {
        float2 dx  = S->du[t4+j][dloc];
        float2 bcv = S->bc[t4+j][n];
        float dA = __expf(dx.x * a);
        state = fmaf(dA, state, dx.y * bcv.x);
        float p = state * bcv.y;
        p += __shfl_xor(p, 1, 64);
        p += __shfl_xor(p, 2, 64);
        p += __shfl_xor(p, 4, 64);
        p += __shfl_xor(p, 8, 64);
        yv[j] = p;
      }
      if (n == 0) *(float4*)&S->ys[dloc][t4] = make_float4(yv[0], yv[1], yv[2], yv[3]);
    }
    __syncthreads();
    for (int idx = tid; idx < TL*16; idx += 256) {
      int t = idx >> 4, cc = idx & 15;
      size_t gi = (tok0 + t0 + t)*DI + ch0 + cc;
      float y  = S->ys[cc][t];
      float uv = fin(uc[gi]);
      float zv = fin(zb[gi]);
      float sz = zv / (1.f + __expf(-zv));
      uc[gi] = (y + uv*S->Dg[cc]) * sz;
    }
    __syncthreads();
  }
}

__global__ __launch_bounds__(256) void k3c(float* uc, const float* zb, const float* dtbc,
    const void* dtp_w, const void* dtp_b, const void* A_log, const void* Dp,
    const float* hloc, const int* flag, int h0, int bg_sh, int lcsh, int nlsh)
{
  extern __shared__ char smem[];
  if (*flag) k3c_body<u16>(uc, zb, dtbc, (const u16*)dtp_w, (const u16*)dtp_b,
                           (const u16*)A_log, (const u16*)Dp, hloc,
                           h0, bg_sh, lcsh, nlsh, smem);
  else       k3c_body<float>(uc, zb, dtbc, (const float*)dtp_w, (const float*)dtp_b,
                           (const float*)A_log, (const float*)Dp, hloc,
                           h0, bg_sh, lcsh, nlsh, smem);
}

// ---------------- K4: out_proj ------------------------------------------
template<typename T>
__device__ void k4_body(const float* yb, const T* w_out, T* out,
                        int h0, int b0, int bg_sh, int tsh, int l_base, char* smem)
{
  const int TILE = 16;
  float (*y_s)[DI] = (float(*)[DI])smem;
  int wg = blockIdx.x;
  int tmask = (1 << tsh) - 1;
  int lt = wg & tmask, c = wg >> tsh;
  int bl = c & ((1 << bg_sh) - 1), hl = c >> bg_sh;
  int h = h0 + hl, b = b0 + bl;
  int tid = threadIdx.x;
  size_t tokbase = (size_t)(c << (tsh+4)) + lt*TILE;
  int l0 = l_base + lt*TILE;
  for (int idx = tid; idx < TILE*DI; idx += 256)
    y_s[idx >> 8][idx & 255] = fin(yb[tokbase*DI + idx]);
  __syncthreads();
  int o = tid & 63, tg = tid >> 6;
  const T* w0r = w_out + ((size_t)h*DH + o)*DI;
  const T* w1r = w0r + (size_t)64*DI;
  float acc0[4] = {0,0,0,0}, acc1[4] = {0,0,0,0};
  for (int ds = 0; ds < DI; ds += 8) {
    float w0[8], w1[8];
    ld8(w0r + ds, w0); ld8(w1r + ds, w1);
    #pragma unroll
    for (int tt = 0; tt < 4; tt++) {
      float4 xa = *(const float4*)&y_s[tg*4+tt][ds];
      float4 xb = *(const float4*)&y_s[tg*4+tt][ds+4];
      acc0[tt] += dot8(xa, xb, w0);
      acc1[tt] += dot8(xa, xb, w1);
    }
  }
  #pragma unroll
  for (int tt = 0; tt < 4; tt++) {
    int l = l0 + tg*4 + tt;
    size_t ob = ((size_t)(b*Ll + l))*Cc + (size_t)h*DH;
    st1(out + ob + o,      acc0[tt]);
    st1(out + ob + o + 64, acc1[tt]);
  }
}

__global__ __launch_bounds__(256) void k4(const float* yb, const void* w_out,
    void* out, const int* flag, int h0, int b0, int bg_sh, int tsh, int l_base)
{
  extern __shared__ char smem[];
  if (*flag) k4_body<u16>(yb, (const u16*)w_out, (u16*)out, h0, b0, bg_sh, tsh, l_base, smem);
  else       k4_body<float>(yb, (const float*)w_out, (float*)out, h0, b0, bg_sh, tsh, l_base, smem);
}

extern "C" void kernel_launch(void* const* d_in, const int* in_sizes, int n_in,
                              void* d_out, int out_size, void* d_ws, size_t ws_size,
                              hipStream_t stream)
{
  const void* x      = d_in[0];
  const void* w_in   = d_in[1];
  const void* conv_w = d_in[2];
  const void* conv_b = d_in[3];
  const void* xp_w   = d_in[4];
  const void* dtp_w  = d_in[5];
  const void* dtp_b  = d_in[6];
  const void* A_log  = d_in[7];
  const void* Dp     = d_in[8];
  const void* w_out  = d_in[9];
  (void)in_sizes; (void)n_in; (void)out_size;

  int* flag = (int*)d_ws;
  detect_dtype<<<1, 256, 0, stream>>>((const u16*)x, flag);

  static const int HGs[] = {8,4,2,1,1,1,1,1,1};
  static const int BGs[] = {4,4,4,4,2,1,1,1,1};
  static const int TSs[] = {8,8,8,8,8,8,6,4,2};
  size_t avail = (ws_size > 256) ? ws_size - 256 : 0;
  int sel = 8;
  for (int i = 0; i < 9; i++) {
    int ts = TSs[i];
    int nlsh_i = (ts > 4) ? (ts - 4) : 0;
    size_t S = (size_t)16 << ts;
    size_t NLs = (size_t)1 << nlsh_i;
    size_t per = S*DI*4*2 + S*40*4 + (size_t)DI*NN*4 + NLs*DI*NN*4 + NLs*DI*4;
    if ((size_t)HGs[i]*BGs[i]*per <= avail) { sel = i; break; }
  }
  int HG = HGs[sel], BG = BGs[sel], tsh = TSs[sel];
  int bg_sh = (BG == 4) ? 2 : (BG == 2) ? 1 : 0;
  int NCH = HG * BG;
  int tps = 1 << tsh;
  int SEG = 16 << tsh;
  int lcsh = 4 + ((tsh < 4) ? tsh : 4);      // chunk length = 16<<min(tsh,4), max 256
  int nlsh = tsh - ((tsh < 4) ? tsh : 4);    // chunks per segment
  int NL = 1 << nlsh;

  float* uc    = (float*)((char*)d_ws + 256);
  float* zb    = uc    + (size_t)NCH*SEG*DI;
  float* dtbc  = zb    + (size_t)NCH*SEG*DI;
  float* state = dtbc  + (size_t)NCH*SEG*40;
  float* hloc  = state + (size_t)NCH*DI*NN;
  float* Sb    = hloc  + (size_t)NCH*NL*DI*NN;

  size_t sm1 = 19*DH*4;
  size_t sm2 = 16*DI*4;
  size_t sm3a = sizeof(K3AS);
  size_t sm3c = sizeof(K3S);
  size_t sm4 = 16*DI*4;
  dim3 blk(256);

  for (int h0 = 0; h0 < Hh; h0 += HG)
    for (int b0 = 0; b0 < Bb; b0 += BG)
      for (int l_base = 0; l_base < Ll; l_base += SEG) {
        k1<<<dim3(NCH*tps), blk, sm1, stream>>>(x, w_in, conv_w, conv_b, uc, zb,
                                                flag, h0, b0, bg_sh, tsh, l_base);
        k2<<<dim3(NCH*tps), blk, sm2, stream>>>(uc, xp_w, dtbc, flag, h0, bg_sh, tsh);
        k3a<<<dim3(NCH*16*NL), blk, sm3a, stream>>>(uc, dtbc, dtp_w, dtp_b, A_log,
                                                hloc, Sb, flag, h0, bg_sh, lcsh, nlsh);
        k3b<<<dim3(NCH*16), blk, 0, stream>>>(hloc, Sb, state, A_log, flag,
                                                h0, bg_sh, nlsh, l_base);
        k3c<<<dim3(NCH*16*NL), blk, sm3c, stream>>>(uc, zb, dtbc, dtp_w, dtp_b, A_log,
                                                Dp, hloc, flag, h0, bg_sh, lcsh, nlsh);
        k4<<<dim3(NCH*tps), blk, sm4, stream>>>(uc, w_out, d_out, flag,
                                                h0, b0, bg_sh, tsh, l_base);
      }
}

// Round 5
// 1152.932 us; speedup vs baseline: 3.0490x; 2.4477x over previous
//
#include <hip/hip_runtime.h>

#define Hh 8
#define Bb 4
#define Ll 4096
#define Cc 1024
#define DH 128
#define DI 256
#define KK 4
#define RR 8
#define NN 16

typedef unsigned short u16;
typedef __bf16 bfv8 __attribute__((ext_vector_type(8)));
typedef float f32x4 __attribute__((ext_vector_type(4)));

__device__ __forceinline__ float bf2f(u16 u) {
  union { unsigned i; float f; } v; v.i = ((unsigned)u) << 16; return v.f;
}
__device__ __forceinline__ u16 f2b(float f) {
  union { float f; unsigned i; } u; u.f = f;
  unsigned lsb = (u.i >> 16) & 1; u.i += 0x7FFFu + lsb; return (u16)(u.i >> 16);
}

// ---- weight preconvert: w_in, w_out -> bf16; xp_w -> bf16 padded 40->48 rows
__global__ __launch_bounds__(256) void kw_conv(const float* __restrict__ w_in,
    const float* __restrict__ w_out, const float* __restrict__ xp_w,
    u16* __restrict__ wibf, u16* __restrict__ wobf, u16* __restrict__ xpbf)
{
  const int N1 = Hh*512*DH, N2 = Hh*DH*DI, N3 = Hh*48*DI;
  for (int i = blockIdx.x*256 + threadIdx.x; i < N1+N2+N3; i += gridDim.x*256) {
    if (i < N1) wibf[i] = f2b(w_in[i]);
    else if (i < N1+N2) wobf[i-N1] = f2b(w_out[i-N1]);
    else {
      int j = i - N1 - N2;
      int k = j & 255, row = (j >> 8) % 48, h = j / (48*256);
      xpbf[j] = (row < 40) ? f2b(xp_w[((size_t)h*40 + row)*DI + k]) : (u16)0;
    }
  }
}

// ---- K1m: in_proj via MFMA. WG = 64 tok x 128 ch; writes u,z bf16. ----
__global__ __launch_bounds__(256) void k1m(const float* __restrict__ x,
    const u16* __restrict__ wibf, u16* __restrict__ ubuf, u16* __restrict__ zbuf,
    int h0, int b0, int bg_sh)
{
  __shared__ u16 x_s[64*136];   // [tok][128k] pad +8 bf16 (bank spread)
  int wg = blockIdx.x;
  int tt = wg & 63, cn = (wg >> 6) & 3, c = wg >> 8;
  int bl = c & ((1 << bg_sh) - 1), hl = c >> bg_sh;
  int h = h0 + hl, b = b0 + bl;
  int tid = threadIdx.x;
  int l0 = tt * 64;

  for (int idx = tid; idx < 64*32; idx += 256) {
    int t = idx >> 5, q = (idx & 31) * 4;
    float4 v = *(const float4*)(x + ((size_t)(b*Ll + l0 + t))*Cc + h*DH + q);
    ushort4 pk = { f2b(v.x), f2b(v.y), f2b(v.z), f2b(v.w) };
    *(ushort4*)&x_s[t*136 + q] = pk;
  }
  __syncthreads();

  int lane = tid & 63, wave = tid >> 6;
  int wm = wave & 1, wn = wave >> 1;
  int lr = lane & 15, quad = lane >> 4;

  f32x4 acc[2][4];
  #pragma unroll
  for (int i = 0; i < 2; i++)
    #pragma unroll
    for (int j = 0; j < 4; j++) acc[i][j] = (f32x4)0.f;

  const u16* wbase = wibf + ((size_t)h*512 + cn*128 + wn*64)*DH;
  #pragma unroll
  for (int ks = 0; ks < 4; ks++) {
    int k0 = ks*32 + quad*8;
    bfv8 a0 = *(const bfv8*)&x_s[(wm*32 + lr)*136 + k0];
    bfv8 a1 = *(const bfv8*)&x_s[(wm*32 + 16 + lr)*136 + k0];
    #pragma unroll
    for (int n4 = 0; n4 < 4; n4++) {
      bfv8 bf = *(const bfv8*)&wbase[(size_t)(n4*16 + lr)*DH + k0];
      acc[0][n4] = __builtin_amdgcn_mfma_f32_16x16x32_bf16(a0, bf, acc[0][n4], 0,0,0);
      acc[1][n4] = __builtin_amdgcn_mfma_f32_16x16x32_bf16(a1, bf, acc[1][n4], 0,0,0);
    }
  }

  u16* obuf = (cn < 2) ? ubuf : zbuf;
  int chbase = (cn & 1)*128 + wn*64;
  size_t rowbase = (size_t)c*Ll + l0;
  #pragma unroll
  for (int m2 = 0; m2 < 2; m2++)
    #pragma unroll
    for (int n4 = 0; n4 < 4; n4++) {
      int ch = chbase + n4*16 + lr;
      #pragma unroll
      for (int r = 0; r < 4; r++) {
        int tok = wm*32 + m2*16 + quad*4 + r;
        obuf[(rowbase + tok)*DI + ch] = f2b(acc[m2][n4][r]);
      }
    }
}

// ---- K1c: causal conv(K=4)+SiLU streaming; u(bf16) -> uc(bf16) ----
__global__ __launch_bounds__(256) void k1c(const u16* __restrict__ ubuf,
    const float* __restrict__ conv_w, const float* __restrict__ conv_b,
    u16* __restrict__ ucbuf, int h0, int bg_sh)
{
  int wg = blockIdx.x;
  int tt = wg & 63, c = wg >> 6;
  int h = h0 + (c >> bg_sh);
  int e = threadIdx.x;
  float4 cw = *(const float4*)&conv_w[((size_t)h*DI + e)*KK];
  float cb = conv_b[h*DI + e];
  size_t base = ((size_t)c*Ll + tt*64)*DI + e;
  float u3, u2, u1;
  if (tt == 0) { u3 = u2 = u1 = 0.f; }
  else {
    u3 = bf2f(ubuf[base - 3*DI]);
    u2 = bf2f(ubuf[base - 2*DI]);
    u1 = bf2f(ubuf[base - 1*DI]);
  }
  #pragma unroll 4
  for (int t = 0; t < 64; t++) {
    float cur = bf2f(ubuf[base + (size_t)t*DI]);
    float acc = cb + u3*cw.x + u2*cw.y + u1*cw.z + cur*cw.w;
    ucbuf[base + (size_t)t*DI] = f2b(acc / (1.f + __expf(-acc)));
    u3 = u2; u2 = u1; u1 = cur;
  }
}

// ---- K2m: x_proj via MFMA (N=48 padded, keep ch<40) -> dtbc f32 ----
__global__ __launch_bounds__(256) void k2m(const u16* __restrict__ ucbuf,
    const u16* __restrict__ xpbf, float* __restrict__ dtbc, int h0, int bg_sh)
{
  __shared__ u16 uc_s[64*264];
  int wg = blockIdx.x;
  int tt = wg & 63, c = wg >> 6;
  int h = h0 + (c >> bg_sh);
  int tid = threadIdx.x;
  size_t rowbase = (size_t)c*Ll + tt*64;

  for (int idx = tid; idx < 64*64; idx += 256) {
    int t = idx >> 6, q = (idx & 63) * 4;
    *(ushort4*)&uc_s[t*264 + q] = *(const ushort4*)&ucbuf[(rowbase + t)*DI + q];
  }
  __syncthreads();

  int lane = tid & 63, wv = tid >> 6;
  int lr = lane & 15, quad = lane >> 4;
  f32x4 acc[3];
  #pragma unroll
  for (int j = 0; j < 3; j++) acc[j] = (f32x4)0.f;

  const u16* bbase = xpbf + (size_t)h*48*DI;
  #pragma unroll
  for (int ks = 0; ks < 8; ks++) {
    int k0 = ks*32 + quad*8;
    bfv8 a = *(const bfv8*)&uc_s[(wv*16 + lr)*264 + k0];
    #pragma unroll
    for (int n4 = 0; n4 < 3; n4++) {
      bfv8 bf = *(const bfv8*)&bbase[(size_t)(n4*16 + lr)*DI + k0];
      acc[n4] = __builtin_amdgcn_mfma_f32_16x16x32_bf16(a, bf, acc[n4], 0,0,0);
    }
  }
  #pragma unroll
  for (int n4 = 0; n4 < 3; n4++) {
    int ch = n4*16 + lr;
    if (ch < 40) {
      #pragma unroll
      for (int r = 0; r < 4; r++) {
        int tok = wv*16 + quad*4 + r;
        dtbc[(rowbase + tok)*40 + ch] = acc[n4][r];
      }
    }
  }
}

// ---- K3a: per-256-token-chunk local scan -> h_local_end + sum_delta ----
struct K3AS {
  float2 du[64][16];
  float  Bv[64][16];
  float  dts[64][8];
  float  wdt[16][8];
  float  bias[16];
};

__global__ __launch_bounds__(256) void k3a(const u16* __restrict__ ucbuf,
    const float* __restrict__ dtbc, const float* __restrict__ dtp_w,
    const float* __restrict__ dtp_b, const float* __restrict__ A_log,
    float* __restrict__ hloc, float* __restrict__ Sb, int h0, int bg_sh)
{
  __shared__ K3AS S;
  const int TL = 64, LC = 256, NL = 16;
  int wg = blockIdx.x;
  int g = wg & 15, nl = (wg >> 4) & 15, c = wg >> 8;
  int h = h0 + (c >> bg_sh);
  int tid = threadIdx.x;
  int dloc = tid >> 4, n = tid & 15;
  int ch0 = g * 16;
  size_t tok0 = (size_t)c*Ll + nl*LC;

  if (tid < 128) S.wdt[tid >> 3][tid & 7] =
      dtp_w[((size_t)(h*DI + ch0 + (tid >> 3)))*RR + (tid & 7)];
  if (tid < 16) S.bias[tid] = dtp_b[h*DI + ch0 + tid];
  float a = -__expf(A_log[((size_t)(h*DI + ch0 + dloc))*NN + n]);
  float state = 0.f, ssum = 0.f;
  __syncthreads();

  for (int t0 = 0; t0 < LC; t0 += TL) {
    for (int idx = tid; idx < TL*8; idx += 256) {
      int t = idx >> 3, r = idx & 7;
      S.dts[t][r] = dtbc[(tok0 + t0 + t)*40 + r];
    }
    for (int idx = tid; idx < TL*16; idx += 256) {
      int t = idx >> 4, j = idx & 15;
      S.Bv[t][j] = dtbc[(tok0 + t0 + t)*40 + 8 + j];
    }
    __syncthreads();
    for (int idx = tid; idx < TL*16; idx += 256) {
      int t = idx >> 4, cc = idx & 15;
      const float* dr = S.dts[t];
      const float* wr = S.wdt[cc];
      float v = S.bias[cc];
      #pragma unroll
      for (int r = 0; r < 8; r++) v += dr[r]*wr[r];
      float delta = (v > 15.f) ? v : log1pf(__expf(v));
      float uv = bf2f(ucbuf[(tok0 + t0 + t)*DI + ch0 + cc]);
      S.du[t][cc] = make_float2(delta, delta * uv);
    }
    __syncthreads();
    #pragma unroll 4
    for (int t = 0; t < TL; t++) {
      float2 dx = S.du[t][dloc];
      float bv = S.Bv[t][n];
      state = fmaf(__expf(dx.x * a), state, dx.y * bv);
      ssum += dx.x;
    }
    __syncthreads();
  }
  hloc[((size_t)(c*NL + nl)*DI + ch0 + dloc)*NN + n] = state;
  if (n == 0) Sb[(size_t)(c*NL + nl)*DI + ch0 + dloc] = ssum;
}

// ---- K3b: compose chunks; hloc becomes per-chunk incoming state ----
__global__ __launch_bounds__(256) void k3b(float* __restrict__ hloc,
    const float* __restrict__ Sb, const float* __restrict__ A_log,
    int h0, int bg_sh)
{
  const int NL = 16;
  int gid = blockIdx.x * 256 + threadIdx.x;
  int c = gid >> 12;
  int r = gid & 4095;
  int d = r >> 4, n = r & 15;
  int h = h0 + (c >> bg_sh);
  float a = -__expf(A_log[((size_t)(h*DI + d))*NN + n]);
  float hin = 0.f;
  for (int k = 0; k < NL; k++) {
    size_t hi = ((size_t)(c*NL + k)*DI + d)*NN + n;
    float tmp = hloc[hi];
    hloc[hi] = hin;
    hin = fmaf(__expf(a * Sb[(size_t)(c*NL + k)*DI + d]), hin, tmp);
  }
}

// ---- K3c: full scan per chunk from h_in; gated y (bf16) into ubuf ----
struct K3S {
  float2 du[64][16];
  float2 bc[64][16];
  float  dts[64][8];
  float  ys[16][68];
  float  wdt[16][8];
  float  bias[16];
  float  Dg[16];
};

__global__ __launch_bounds__(256) void k3c(const u16* __restrict__ ucbuf,
    const u16* __restrict__ zbuf, const float* __restrict__ dtbc,
    const float* __restrict__ dtp_w, const float* __restrict__ dtp_b,
    const float* __restrict__ A_log, const float* __restrict__ Dp,
    const float* __restrict__ hloc, u16* __restrict__ ybuf, int h0, int bg_sh)
{
  __shared__ K3S S;
  const int TL = 64, LC = 256, NL = 16;
  int wg = blockIdx.x;
  int g = wg & 15, nl = (wg >> 4) & 15, c = wg >> 8;
  int h = h0 + (c >> bg_sh);
  int tid = threadIdx.x;
  int dloc = tid >> 4, n = tid & 15;
  int ch0 = g * 16;
  size_t tok0 = (size_t)c*Ll + nl*LC;

  if (tid < 128) S.wdt[tid >> 3][tid & 7] =
      dtp_w[((size_t)(h*DI + ch0 + (tid >> 3)))*RR + (tid & 7)];
  if (tid < 16) {
    S.bias[tid] = dtp_b[h*DI + ch0 + tid];
    S.Dg[tid]   = Dp[h*DI + ch0 + tid];
  }
  float a = -__expf(A_log[((size_t)(h*DI + ch0 + dloc))*NN + n]);
  float state = hloc[((size_t)(c*NL + nl)*DI + ch0 + dloc)*NN + n];
  __syncthreads();

  for (int t0 = 0; t0 < LC; t0 += TL) {
    for (int idx = tid; idx < TL*8; idx += 256) {
      int t = idx >> 3, r = idx & 7;
      S.dts[t][r] = dtbc[(tok0 + t0 + t)*40 + r];
    }
    for (int idx = tid; idx < TL*32; idx += 256) {
      int t = idx >> 5, j = idx & 31;
      float v = dtbc[(tok0 + t0 + t)*40 + 8 + j];
      ((float*)&S.bc[t][0])[(j < 16) ? (2*j) : (2*(j-16)+1)] = v;
    }
    __syncthreads();
    for (int idx = tid; idx < TL*16; idx += 256) {
      int t = idx >> 4, cc = idx & 15;
      const float* dr = S.dts[t];
      const float* wr = S.wdt[cc];
      float v = S.bias[cc];
      #pragma unroll
      for (int r = 0; r < 8; r++) v += dr[r]*wr[r];
      float delta = (v > 15.f) ? v : log1pf(__expf(v));
      float uv = bf2f(ucbuf[(tok0 + t0 + t)*DI + ch0 + cc]);
      S.du[t][cc] = make_float2(delta, delta * uv);
    }
    __syncthreads();
    #pragma unroll
    for (int t4 = 0; t4 < TL; t4 += 4) {
      float yv[4];
      #pragma unroll
      for (int j = 0; j < 4; j++) {
        float2 dx  = S.du[t4+j][dloc];
        float2 bcv = S.bc[t4+j][n];
        state = fmaf(__expf(dx.x * a), state, dx.y * bcv.x);
        float p = state * bcv.y;
        p += __shfl_xor(p, 1, 64);
        p += __shfl_xor(p, 2, 64);
        p += __shfl_xor(p, 4, 64);
        p += __shfl_xor(p, 8, 64);
        yv[j] = p;
      }
      if (n == 0) *(float4*)&S.ys[dloc][t4] = make_float4(yv[0], yv[1], yv[2], yv[3]);
    }
    __syncthreads();
    for (int idx = tid; idx < TL*16; idx += 256) {
      int t = idx >> 4, cc = idx & 15;
      size_t gi = (tok0 + t0 + t)*DI + ch0 + cc;
      float y  = S.ys[cc][t];
      float uv = bf2f(ucbuf[gi]);
      float zv = bf2f(zbuf[gi]);
      float sz = zv / (1.f + __expf(-zv));
      ybuf[gi] = f2b((y + uv*S.Dg[cc]) * sz);
    }
    __syncthreads();
  }
}

// ---- K4m: out_proj via MFMA; writes f32 output ----
__global__ __launch_bounds__(256) void k4m(const u16* __restrict__ ybuf,
    const u16* __restrict__ wobf, float* __restrict__ out,
    int h0, int b0, int bg_sh)
{
  __shared__ u16 y_s[64*264];
  int wg = blockIdx.x;
  int tt = wg & 63, c = wg >> 6;
  int bl = c & ((1 << bg_sh) - 1), hl = c >> bg_sh;
  int h = h0 + hl, b = b0 + bl;
  int tid = threadIdx.x;
  size_t rowbase = (size_t)c*Ll + tt*64;

  for (int idx = tid; idx < 64*64; idx += 256) {
    int t = idx >> 6, q = (idx & 63) * 4;
    *(ushort4*)&y_s[t*264 + q] = *(const ushort4*)&ybuf[(rowbase + t)*DI + q];
  }
  __syncthreads();

  int lane = tid & 63, wave = tid >> 6;
  int wm = wave & 1, wn = wave >> 1;
  int lr = lane & 15, quad = lane >> 4;

  f32x4 acc[2][4];
  #pragma unroll
  for (int i = 0; i < 2; i++)
    #pragma unroll
    for (int j = 0; j < 4; j++) acc[i][j] = (f32x4)0.f;

  const u16* wbase = wobf + ((size_t)h*DH + wn*64)*DI;
  #pragma unroll
  for (int ks = 0; ks < 8; ks++) {
    int k0 = ks*32 + quad*8;
    bfv8 a0 = *(const bfv8*)&y_s[(wm*32 + lr)*264 + k0];
    bfv8 a1 = *(const bfv8*)&y_s[(wm*32 + 16 + lr)*264 + k0];
    #pragma unroll
    for (int n4 = 0; n4 < 4; n4++) {
      bfv8 bf = *(const bfv8*)&wbase[(size_t)(n4*16 + lr)*DI + k0];
      acc[0][n4] = __builtin_amdgcn_mfma_f32_16x16x32_bf16(a0, bf, acc[0][n4], 0,0,0);
      acc[1][n4] = __builtin_amdgcn_mfma_f32_16x16x32_bf16(a1, bf, acc[1][n4], 0,0,0);
    }
  }

  #pragma unroll
  for (int m2 = 0; m2 < 2; m2++)
    #pragma unroll
    for (int n4 = 0; n4 < 4; n4++) {
      int ch = wn*64 + n4*16 + lr;
      #pragma unroll
      for (int r = 0; r < 4; r++) {
        int l = tt*64 + wm*32 + m2*16 + quad*4 + r;
        out[((size_t)(b*Ll + l))*Cc + h*DH + ch] = acc[m2][n4][r];
      }
    }
}

extern "C" void kernel_launch(void* const* d_in, const int* in_sizes, int n_in,
                              void* d_out, int out_size, void* d_ws, size_t ws_size,
                              hipStream_t stream)
{
  const float* x      = (const float*)d_in[0];
  const float* w_in   = (const float*)d_in[1];
  const float* conv_w = (const float*)d_in[2];
  const float* conv_b = (const float*)d_in[3];
  const float* xp_w   = (const float*)d_in[4];
  const float* dtp_w  = (const float*)d_in[5];
  const float* dtp_b  = (const float*)d_in[6];
  const float* A_log  = (const float*)d_in[7];
  const float* Dp     = (const float*)d_in[8];
  const float* w_out  = (const float*)d_in[9];
  (void)in_sizes; (void)n_in; (void)out_size;

  const size_t NW1 = (size_t)Hh*512*DH, NW2 = (size_t)Hh*DH*DI, NW3 = (size_t)Hh*48*DI;
  size_t wbytes = ((NW1 + NW2 + NW3)*2 + 255) & ~(size_t)255;
  // per-(h,b) slice: u,z,uc bf16 + dtbc f32 + hloc + Sb
  size_t per = (size_t)Ll*DI*2*3 + (size_t)Ll*40*4 + (size_t)16*DI*NN*4 + (size_t)16*DI*4;

  static const int HGs[] = {8,4,2,1,1,1};
  static const int BGs[] = {4,4,4,4,2,1};
  int sel = 5;
  for (int i = 0; i < 6; i++)
    if (wbytes + (size_t)HGs[i]*BGs[i]*per <= ws_size) { sel = i; break; }
  int HG = HGs[sel], BG = BGs[sel];
  int bg_sh = (BG == 4) ? 2 : (BG == 2) ? 1 : 0;
  int NCH = HG * BG;

  char* p = (char*)d_ws;
  u16* wibf = (u16*)p; p += NW1*2;
  u16* wobf = (u16*)p; p += NW2*2;
  u16* xpbf = (u16*)p; p += NW3*2;
  p = (char*)(((uintptr_t)p + 255) & ~(uintptr_t)255);
  u16* ubuf  = (u16*)p; p += (size_t)NCH*Ll*DI*2;   // u, later y
  u16* zbuf  = (u16*)p; p += (size_t)NCH*Ll*DI*2;
  u16* ucbuf = (u16*)p; p += (size_t)NCH*Ll*DI*2;
  float* dtbc = (float*)p; p += (size_t)NCH*Ll*40*4;
  float* hloc = (float*)p; p += (size_t)NCH*16*DI*NN*4;
  float* Sb   = (float*)p;

  dim3 blk(256);
  kw_conv<<<dim3(512), blk, 0, stream>>>(w_in, w_out, xp_w, wibf, wobf, xpbf);

  for (int h0 = 0; h0 < Hh; h0 += HG)
    for (int b0 = 0; b0 < Bb; b0 += BG) {
      k1m<<<dim3(NCH*256), blk, 0, stream>>>(x, wibf, ubuf, zbuf, h0, b0, bg_sh);
      k1c<<<dim3(NCH*64),  blk, 0, stream>>>(ubuf, conv_w, conv_b, ucbuf, h0, bg_sh);
      k2m<<<dim3(NCH*64),  blk, 0, stream>>>(ucbuf, xpbf, dtbc, h0, bg_sh);
      k3a<<<dim3(NCH*256), blk, 0, stream>>>(ucbuf, dtbc, dtp_w, dtp_b, A_log,
                                             hloc, Sb, h0, bg_sh);
      k3b<<<dim3(NCH*16),  blk, 0, stream>>>(hloc, Sb, A_log, h0, bg_sh);
      k3c<<<dim3(NCH*256), blk, 0, stream>>>(ucbuf, zbuf, dtbc, dtp_w, dtp_b, A_log,
                                             Dp, hloc, ubuf, h0, bg_sh);
      k4m<<<dim3(NCH*64),  blk, 0, stream>>>(ubuf, wobf, (float*)d_out, h0, b0, bg_sh);
    }
}

// Round 6
// 928.681 us; speedup vs baseline: 3.7852x; 1.2415x over previous
//
#include <hip/hip_runtime.h>

#define Hh 8
#define Bb 4
#define Ll 4096
#define Cc 1024
#define DH 128
#define DI 256
#define KK 4
#define RR 8
#define NN 16

typedef unsigned short u16;
typedef __bf16 bfv8 __attribute__((ext_vector_type(8)));
typedef float f32x4 __attribute__((ext_vector_type(4)));

__device__ __forceinline__ float bf2f(u16 u) {
  union { unsigned i; float f; } v; v.i = ((unsigned)u) << 16; return v.f;
}
__device__ __forceinline__ u16 f2b(float f) {
  union { float f; unsigned i; } u; u.f = f;
  unsigned lsb = (u.i >> 16) & 1; u.i += 0x7FFFu + lsb; return (u16)(u.i >> 16);
}

// ---- weight preconvert: w_in, w_out -> bf16; xp_w -> bf16 padded 40->48 rows
__global__ __launch_bounds__(256) void kw_conv(const float* __restrict__ w_in,
    const float* __restrict__ w_out, const float* __restrict__ xp_w,
    u16* __restrict__ wibf, u16* __restrict__ wobf, u16* __restrict__ xpbf)
{
  const int N1 = Hh*512*DH, N2 = Hh*DH*DI, N3 = Hh*48*DI;
  for (int i = blockIdx.x*256 + threadIdx.x; i < N1+N2+N3; i += gridDim.x*256) {
    if (i < N1) wibf[i] = f2b(w_in[i]);
    else if (i < N1+N2) wobf[i-N1] = f2b(w_out[i-N1]);
    else {
      int j = i - N1 - N2;
      int k = j & 255, row = (j >> 8) % 48, h = j / (48*256);
      xpbf[j] = (row < 40) ? f2b(xp_w[((size_t)h*40 + row)*DI + k]) : (u16)0;
    }
  }
}

// ---- K1m: in_proj via MFMA. WG = 64 tok x 128 ch; writes u,z bf16. ----
__global__ __launch_bounds__(256) void k1m(const float* __restrict__ x,
    const u16* __restrict__ wibf, u16* __restrict__ ubuf, u16* __restrict__ zbuf,
    int h0, int b0, int bg_sh)
{
  __shared__ u16 x_s[64*136];   // [tok][128k] pad +8 bf16 (bank spread)
  int wg = blockIdx.x;
  int tt = wg & 63, cn = (wg >> 6) & 3, c = wg >> 8;
  int bl = c & ((1 << bg_sh) - 1), hl = c >> bg_sh;
  int h = h0 + hl, b = b0 + bl;
  int tid = threadIdx.x;
  int l0 = tt * 64;

  for (int idx = tid; idx < 64*32; idx += 256) {
    int t = idx >> 5, q = (idx & 31) * 4;
    float4 v = *(const float4*)(x + ((size_t)(b*Ll + l0 + t))*Cc + h*DH + q);
    ushort4 pk = { f2b(v.x), f2b(v.y), f2b(v.z), f2b(v.w) };
    *(ushort4*)&x_s[t*136 + q] = pk;
  }
  __syncthreads();

  int lane = tid & 63, wave = tid >> 6;
  int wm = wave & 1, wn = wave >> 1;
  int lr = lane & 15, quad = lane >> 4;

  f32x4 acc[2][4];
  #pragma unroll
  for (int i = 0; i < 2; i++)
    #pragma unroll
    for (int j = 0; j < 4; j++) acc[i][j] = (f32x4)0.f;

  const u16* wbase = wibf + ((size_t)h*512 + cn*128 + wn*64)*DH;
  #pragma unroll
  for (int ks = 0; ks < 4; ks++) {
    int k0 = ks*32 + quad*8;
    bfv8 a0 = *(const bfv8*)&x_s[(wm*32 + lr)*136 + k0];
    bfv8 a1 = *(const bfv8*)&x_s[(wm*32 + 16 + lr)*136 + k0];
    #pragma unroll
    for (int n4 = 0; n4 < 4; n4++) {
      bfv8 bf = *(const bfv8*)&wbase[(size_t)(n4*16 + lr)*DH + k0];
      acc[0][n4] = __builtin_amdgcn_mfma_f32_16x16x32_bf16(a0, bf, acc[0][n4], 0,0,0);
      acc[1][n4] = __builtin_amdgcn_mfma_f32_16x16x32_bf16(a1, bf, acc[1][n4], 0,0,0);
    }
  }

  u16* obuf = (cn < 2) ? ubuf : zbuf;
  int chbase = (cn & 1)*128 + wn*64;
  size_t rowbase = (size_t)c*Ll + l0;
  #pragma unroll
  for (int m2 = 0; m2 < 2; m2++)
    #pragma unroll
    for (int n4 = 0; n4 < 4; n4++) {
      int ch = chbase + n4*16 + lr;
      #pragma unroll
      for (int r = 0; r < 4; r++) {
        int tok = wm*32 + m2*16 + quad*4 + r;
        obuf[(rowbase + tok)*DI + ch] = f2b(acc[m2][n4][r]);
      }
    }
}

// ---- K1c: causal conv(K=4)+SiLU streaming; u(bf16) -> uc(bf16) ----
__global__ __launch_bounds__(256) void k1c(const u16* __restrict__ ubuf,
    const float* __restrict__ conv_w, const float* __restrict__ conv_b,
    u16* __restrict__ ucbuf, int h0, int bg_sh)
{
  int wg = blockIdx.x;
  int tt = wg & 63, c = wg >> 6;
  int h = h0 + (c >> bg_sh);
  int e = threadIdx.x;
  float4 cw = *(const float4*)&conv_w[((size_t)h*DI + e)*KK];
  float cb = conv_b[h*DI + e];
  size_t base = ((size_t)c*Ll + tt*64)*DI + e;
  float u3, u2, u1;
  if (tt == 0) { u3 = u2 = u1 = 0.f; }
  else {
    u3 = bf2f(ubuf[base - 3*DI]);
    u2 = bf2f(ubuf[base - 2*DI]);
    u1 = bf2f(ubuf[base - 1*DI]);
  }
  #pragma unroll 4
  for (int t = 0; t < 64; t++) {
    float cur = bf2f(ubuf[base + (size_t)t*DI]);
    float acc = cb + u3*cw.x + u2*cw.y + u1*cw.z + cur*cw.w;
    ucbuf[base + (size_t)t*DI] = f2b(acc / (1.f + __expf(-acc)));
    u3 = u2; u2 = u1; u1 = cur;
  }
}

// ---- K2m: x_proj via MFMA (N=48 padded, keep ch<40) -> dtbc f32 ----
__global__ __launch_bounds__(256) void k2m(const u16* __restrict__ ucbuf,
    const u16* __restrict__ xpbf, float* __restrict__ dtbc, int h0, int bg_sh)
{
  __shared__ u16 uc_s[64*264];
  int wg = blockIdx.x;
  int tt = wg & 63, c = wg >> 6;
  int h = h0 + (c >> bg_sh);
  int tid = threadIdx.x;
  size_t rowbase = (size_t)c*Ll + tt*64;

  for (int idx = tid; idx < 64*64; idx += 256) {
    int t = idx >> 6, q = (idx & 63) * 4;
    *(ushort4*)&uc_s[t*264 + q] = *(const ushort4*)&ucbuf[(rowbase + t)*DI + q];
  }
  __syncthreads();

  int lane = tid & 63, wv = tid >> 6;
  int lr = lane & 15, quad = lane >> 4;
  f32x4 acc[3];
  #pragma unroll
  for (int j = 0; j < 3; j++) acc[j] = (f32x4)0.f;

  const u16* bbase = xpbf + (size_t)h*48*DI;
  #pragma unroll
  for (int ks = 0; ks < 8; ks++) {
    int k0 = ks*32 + quad*8;
    bfv8 a = *(const bfv8*)&uc_s[(wv*16 + lr)*264 + k0];
    #pragma unroll
    for (int n4 = 0; n4 < 3; n4++) {
      bfv8 bf = *(const bfv8*)&bbase[(size_t)(n4*16 + lr)*DI + k0];
      acc[n4] = __builtin_amdgcn_mfma_f32_16x16x32_bf16(a, bf, acc[n4], 0,0,0);
    }
  }
  #pragma unroll
  for (int n4 = 0; n4 < 3; n4++) {
    int ch = n4*16 + lr;
    if (ch < 40) {
      #pragma unroll
      for (int r = 0; r < 4; r++) {
        int tok = wv*16 + quad*4 + r;
        dtbc[(rowbase + tok)*40 + ch] = acc[n4][r];
      }
    }
  }
}

// ---- K3a: per-256-token-chunk local scan, thread = channel d. ----
// All 16 n-states in VGPRs; dt/B rows are wave-uniform -> SGPR loads.
// No LDS, no barriers, no cross-lane ops.
__global__ __launch_bounds__(256) void k3a(const u16* __restrict__ ucbuf,
    const float* __restrict__ dtbc, const float* __restrict__ dtp_w,
    const float* __restrict__ dtp_b, const float* __restrict__ A_log,
    float* __restrict__ hloc, float* __restrict__ Sb, int h0, int bg_sh)
{
  const int LC = 256, NL = 16;
  int wg = blockIdx.x;
  int nl = wg & 15, c = wg >> 4;
  int h = h0 + (c >> bg_sh);
  int d = threadIdx.x;
  size_t tok0 = (size_t)c*Ll + nl*LC;

  float a[NN];
  #pragma unroll
  for (int n = 0; n < NN; n += 4) {
    float4 v = *(const float4*)&A_log[((size_t)(h*DI + d))*NN + n];
    a[n] = -__expf(v.x); a[n+1] = -__expf(v.y);
    a[n+2] = -__expf(v.z); a[n+3] = -__expf(v.w);
  }
  float wdt[RR];
  #pragma unroll
  for (int r = 0; r < RR; r += 4)
    *(float4*)&wdt[r] = *(const float4*)&dtp_w[((size_t)(h*DI + d))*RR + r];
  float bias = dtp_b[h*DI + d];

  float st[NN];
  #pragma unroll
  for (int n = 0; n < NN; n++) st[n] = 0.f;
  float ssum = 0.f;

  #pragma unroll 2
  for (int t = 0; t < LC; t++) {
    const float* row = dtbc + (tok0 + t)*40;   // wave-uniform -> s_load
    float v = bias;
    #pragma unroll
    for (int r = 0; r < RR; r++) v += row[r]*wdt[r];
    float delta = (v > 15.f) ? v : log1pf(__expf(v));
    float ucv = bf2f(ucbuf[(tok0 + t)*DI + d]);
    float dBu = delta * ucv;
    ssum += delta;
    #pragma unroll
    for (int n = 0; n < NN; n++)
      st[n] = fmaf(__expf(delta*a[n]), st[n], dBu * row[8+n]);
  }
  #pragma unroll
  for (int n = 0; n < NN; n += 4)
    *(float4*)&hloc[((size_t)(c*NL + nl)*DI + d)*NN + n] =
        make_float4(st[n], st[n+1], st[n+2], st[n+3]);
  Sb[(size_t)(c*NL + nl)*DI + d] = ssum;
}

// ---- K3b: compose chunks; hloc becomes per-chunk incoming state ----
__global__ __launch_bounds__(256) void k3b(float* __restrict__ hloc,
    const float* __restrict__ Sb, const float* __restrict__ A_log,
    int h0, int bg_sh)
{
  const int NL = 16;
  int gid = blockIdx.x * 256 + threadIdx.x;
  int c = gid >> 12;
  int r = gid & 4095;
  int d = r >> 4, n = r & 15;
  int h = h0 + (c >> bg_sh);
  float a = -__expf(A_log[((size_t)(h*DI + d))*NN + n]);
  float hin = 0.f;
  for (int k = 0; k < NL; k++) {
    size_t hi = ((size_t)(c*NL + k)*DI + d)*NN + n;
    float tmp = hloc[hi];
    hloc[hi] = hin;
    hin = fmaf(__expf(a * Sb[(size_t)(c*NL + k)*DI + d]), hin, tmp);
  }
}

// ---- K3c: full scan per chunk from h_in, thread = channel d; ----
// emits gated y (bf16) into ybuf. Same structure as k3a + C-reduce + gate.
__global__ __launch_bounds__(256) void k3c(const u16* __restrict__ ucbuf,
    const u16* __restrict__ zbuf, const float* __restrict__ dtbc,
    const float* __restrict__ dtp_w, const float* __restrict__ dtp_b,
    const float* __restrict__ A_log, const float* __restrict__ Dp,
    const float* __restrict__ hloc, u16* __restrict__ ybuf, int h0, int bg_sh)
{
  const int LC = 256, NL = 16;
  int wg = blockIdx.x;
  int nl = wg & 15, c = wg >> 4;
  int h = h0 + (c >> bg_sh);
  int d = threadIdx.x;
  size_t tok0 = (size_t)c*Ll + nl*LC;

  float a[NN];
  #pragma unroll
  for (int n = 0; n < NN; n += 4) {
    float4 v = *(const float4*)&A_log[((size_t)(h*DI + d))*NN + n];
    a[n] = -__expf(v.x); a[n+1] = -__expf(v.y);
    a[n+2] = -__expf(v.z); a[n+3] = -__expf(v.w);
  }
  float wdt[RR];
  #pragma unroll
  for (int r = 0; r < RR; r += 4)
    *(float4*)&wdt[r] = *(const float4*)&dtp_w[((size_t)(h*DI + d))*RR + r];
  float bias = dtp_b[h*DI + d];
  float Dv = Dp[h*DI + d];

  float st[NN];
  #pragma unroll
  for (int n = 0; n < NN; n += 4) {
    float4 v = *(const float4*)&hloc[((size_t)(c*NL + nl)*DI + d)*NN + n];
    st[n] = v.x; st[n+1] = v.y; st[n+2] = v.z; st[n+3] = v.w;
  }

  #pragma unroll 2
  for (int t = 0; t < LC; t++) {
    const float* row = dtbc + (tok0 + t)*40;   // wave-uniform -> s_load
    float v = bias;
    #pragma unroll
    for (int r = 0; r < RR; r++) v += row[r]*wdt[r];
    float delta = (v > 15.f) ? v : log1pf(__expf(v));
    float ucv = bf2f(ucbuf[(tok0 + t)*DI + d]);
    float dBu = delta * ucv;
    float y = 0.f;
    #pragma unroll
    for (int n = 0; n < NN; n++) {
      st[n] = fmaf(__expf(delta*a[n]), st[n], dBu * row[8+n]);
      y = fmaf(st[n], row[24+n], y);
    }
    float zv = bf2f(zbuf[(tok0 + t)*DI + d]);
    float sz = zv / (1.f + __expf(-zv));
    ybuf[(tok0 + t)*DI + d] = f2b((y + ucv*Dv) * sz);
  }
}

// ---- K4m: out_proj via MFMA; writes f32 output ----
__global__ __launch_bounds__(256) void k4m(const u16* __restrict__ ybuf,
    const u16* __restrict__ wobf, float* __restrict__ out,
    int h0, int b0, int bg_sh)
{
  __shared__ u16 y_s[64*264];
  int wg = blockIdx.x;
  int tt = wg & 63, c = wg >> 6;
  int bl = c & ((1 << bg_sh) - 1), hl = c >> bg_sh;
  int h = h0 + hl, b = b0 + bl;
  int tid = threadIdx.x;
  size_t rowbase = (size_t)c*Ll + tt*64;

  for (int idx = tid; idx < 64*64; idx += 256) {
    int t = idx >> 6, q = (idx & 63) * 4;
    *(ushort4*)&y_s[t*264 + q] = *(const ushort4*)&ybuf[(rowbase + t)*DI + q];
  }
  __syncthreads();

  int lane = tid & 63, wave = tid >> 6;
  int wm = wave & 1, wn = wave >> 1;
  int lr = lane & 15, quad = lane >> 4;

  f32x4 acc[2][4];
  #pragma unroll
  for (int i = 0; i < 2; i++)
    #pragma unroll
    for (int j = 0; j < 4; j++) acc[i][j] = (f32x4)0.f;

  const u16* wbase = wobf + ((size_t)h*DH + wn*64)*DI;
  #pragma unroll
  for (int ks = 0; ks < 8; ks++) {
    int k0 = ks*32 + quad*8;
    bfv8 a0 = *(const bfv8*)&y_s[(wm*32 + lr)*264 + k0];
    bfv8 a1 = *(const bfv8*)&y_s[(wm*32 + 16 + lr)*264 + k0];
    #pragma unroll
    for (int n4 = 0; n4 < 4; n4++) {
      bfv8 bf = *(const bfv8*)&wbase[(size_t)(n4*16 + lr)*DI + k0];
      acc[0][n4] = __builtin_amdgcn_mfma_f32_16x16x32_bf16(a0, bf, acc[0][n4], 0,0,0);
      acc[1][n4] = __builtin_amdgcn_mfma_f32_16x16x32_bf16(a1, bf, acc[1][n4], 0,0,0);
    }
  }

  #pragma unroll
  for (int m2 = 0; m2 < 2; m2++)
    #pragma unroll
    for (int n4 = 0; n4 < 4; n4++) {
      int ch = wn*64 + n4*16 + lr;
      #pragma unroll
      for (int r = 0; r < 4; r++) {
        int l = tt*64 + wm*32 + m2*16 + quad*4 + r;
        out[((size_t)(b*Ll + l))*Cc + h*DH + ch] = acc[m2][n4][r];
      }
    }
}

extern "C" void kernel_launch(void* const* d_in, const int* in_sizes, int n_in,
                              void* d_out, int out_size, void* d_ws, size_t ws_size,
                              hipStream_t stream)
{
  const float* x      = (const float*)d_in[0];
  const float* w_in   = (const float*)d_in[1];
  const float* conv_w = (const float*)d_in[2];
  const float* conv_b = (const float*)d_in[3];
  const float* xp_w   = (const float*)d_in[4];
  const float* dtp_w  = (const float*)d_in[5];
  const float* dtp_b  = (const float*)d_in[6];
  const float* A_log  = (const float*)d_in[7];
  const float* Dp     = (const float*)d_in[8];
  const float* w_out  = (const float*)d_in[9];
  (void)in_sizes; (void)n_in; (void)out_size;

  const size_t NW1 = (size_t)Hh*512*DH, NW2 = (size_t)Hh*DH*DI, NW3 = (size_t)Hh*48*DI;
  size_t wbytes = ((NW1 + NW2 + NW3)*2 + 255) & ~(size_t)255;
  // per-(h,b) slice: u,z,uc bf16 + dtbc f32 + hloc + Sb
  size_t per = (size_t)Ll*DI*2*3 + (size_t)Ll*40*4 + (size_t)16*DI*NN*4 + (size_t)16*DI*4;

  static const int HGs[] = {8,4,2,1,1,1};
  static const int BGs[] = {4,4,4,4,2,1};
  int sel = 5;
  for (int i = 0; i < 6; i++)
    if (wbytes + (size_t)HGs[i]*BGs[i]*per <= ws_size) { sel = i; break; }
  int HG = HGs[sel], BG = BGs[sel];
  int bg_sh = (BG == 4) ? 2 : (BG == 2) ? 1 : 0;
  int NCH = HG * BG;

  char* p = (char*)d_ws;
  u16* wibf = (u16*)p; p += NW1*2;
  u16* wobf = (u16*)p; p += NW2*2;
  u16* xpbf = (u16*)p; p += NW3*2;
  p = (char*)(((uintptr_t)p + 255) & ~(uintptr_t)255);
  u16* ubuf  = (u16*)p; p += (size_t)NCH*Ll*DI*2;   // u, later y
  u16* zbuf  = (u16*)p; p += (size_t)NCH*Ll*DI*2;
  u16* ucbuf = (u16*)p; p += (size_t)NCH*Ll*DI*2;
  float* dtbc = (float*)p; p += (size_t)NCH*Ll*40*4;
  float* hloc = (float*)p; p += (size_t)NCH*16*DI*NN*4;
  float* Sb   = (float*)p;

  dim3 blk(256);
  kw_conv<<<dim3(512), blk, 0, stream>>>(w_in, w_out, xp_w, wibf, wobf, xpbf);

  for (int h0 = 0; h0 < Hh; h0 += HG)
    for (int b0 = 0; b0 < Bb; b0 += BG) {
      k1m<<<dim3(NCH*256), blk, 0, stream>>>(x, wibf, ubuf, zbuf, h0, b0, bg_sh);
      k1c<<<dim3(NCH*64),  blk, 0, stream>>>(ubuf, conv_w, conv_b, ucbuf, h0, bg_sh);
      k2m<<<dim3(NCH*64),  blk, 0, stream>>>(ucbuf, xpbf, dtbc, h0, bg_sh);
      k3a<<<dim3(NCH*16),  blk, 0, stream>>>(ucbuf, dtbc, dtp_w, dtp_b, A_log,
                                             hloc, Sb, h0, bg_sh);
      k3b<<<dim3(NCH*16),  blk, 0, stream>>>(hloc, Sb, A_log, h0, bg_sh);
      k3c<<<dim3(NCH*16),  blk, 0, stream>>>(ucbuf, zbuf, dtbc, dtp_w, dtp_b, A_log,
                                             Dp, hloc, ubuf, h0, bg_sh);
      k4m<<<dim3(NCH*64),  blk, 0, stream>>>(ubuf, wobf, (float*)d_out, h0, b0, bg_sh);
    }
}